// Round 7
// baseline (407.151 us; speedup 1.0000x reference)
//
#include <hip/hip_runtime.h>
#include <hip/hip_bf16.h>

// EmbeddingRNN via MFMA, round 7: fit the live set under the 128-VGPR budget
// the toolchain empirically always picks (R2-R6: VGPR_Count==128, FETCH_SIZE
// tracked estimated register-pressure overflow -> scratch spills).
// 256 blocks x 16 waves (1024 thr) x 32 rows; wave owns d in [w*16, w*16+16)
// across 4 gates -> acc[2][4]=32 regs, B-frags 16/kt. Static live ~121 <= 128.
//   phase 0a: embWp = pack(emb @ W + b): thread's 4 gate vals contiguous (float4)
//   phase 0b: Upack = U as bf16 MFMA B-fragments, 16-wave-slice-major
//   phase 1:  fused 16-step recurrence; kt=0 B resident, kt=1..7 2-deep pipeline;
//             h f32 in LDS (XOR-swizzled), double-buffered, 1 barrier/step.

#define DD      256
#define G4      1024
#define NCHAR   155
#define TSTEPS  16
#define RTILE   32
#define NROWS   8192
#define NBLOCKS (NROWS / RTILE)   // 256
#define NTHREADS 1024             // 16 waves

typedef __attribute__((ext_vector_type(8))) short bf16x8;
typedef __attribute__((ext_vector_type(4))) float f32x4;

__device__ inline short f2bf(float f) {
    __hip_bfloat16 h = __float2bfloat16(f);   // RTNE
    return *reinterpret_cast<short*>(&h);
}

// ---------------- phase 0a: embWp = pack(emb @ W + b) ----------------
// embWp[(i*256 + d)*4 + g] = (emb@W+b)[i][g*256+d]  -> one float4 per (i,d)
__global__ __launch_bounds__(256)
void embw_kernel(const float* __restrict__ emb, const float* __restrict__ W,
                 const float* __restrict__ b, float* __restrict__ embWp) {
    const int i   = blockIdx.x;
    const int tid = threadIdx.x;                 // d = tid
    float a0 = b[tid], a1 = b[256 + tid], a2 = b[512 + tid], a3 = b[768 + tid];
    const float* er = emb + i * DD;
    for (int k = 0; k < DD; ++k) {
        const float e = er[k];
        const float* wr = W + k * G4 + tid;
        a0 += e * wr[0];
        a1 += e * wr[256];
        a2 += e * wr[512];
        a3 += e * wr[768];
    }
    float* o = embWp + (i * 256 + tid) * 4;
    o[0] = a0; o[1] = a1; o[2] = a2; o[3] = a3;
}

// ---------------- phase 0b: pack U into bf16 MFMA B-fragments ----------------
// up[((w*8 + kt)*4 + g)*64 + lane]: lane l holds
//   U[kt*32 + (l>>4)*8 + j][g*256 + w*16 + (l&15)], j = 0..7
__global__ __launch_bounds__(256)
void upack_kernel(const float* __restrict__ U, bf16x8* __restrict__ up) {
    const int gid  = blockIdx.x * 256 + threadIdx.x;   // 32768 total
    const int lane = gid & 63;
    const int g    = (gid >> 6) & 3;
    const int kt   = (gid >> 8) & 7;
    const int w    = gid >> 11;
    const int col  = g * 256 + w * 16 + (lane & 15);
    const int k0   = kt * 32 + (lane >> 4) * 8;
    bf16x8 v;
#pragma unroll
    for (int j = 0; j < 8; ++j) v[j] = f2bf(U[(k0 + j) * G4 + col]);
    up[gid] = v;
}

// ---------------- phase 1: fused recurrence ----------------

// A-fragments (both mt) for K-tile KT from swizzled f32 LDS, then 8 MFMAs
#define AFR_MFMA(KT, BARR)                                                      \
    {                                                                           \
        bf16x8 afr0, afr1;                                                      \
        _Pragma("unroll")                                                       \
        for (int mt = 0; mt < 2; ++mt) {                                        \
            const int row = mt * 16 + l15;                                      \
            const int kb  = (KT) * 32 + lg * 8;                                 \
            const int sw  = (row & 15) << 2;                                    \
            const float4 f0 = *(const float4*)&rb[(row * DD + kb) ^ sw];        \
            const float4 f1 = *(const float4*)&rb[(row * DD + kb + 4) ^ sw];    \
            bf16x8 a;                                                           \
            a[0] = f2bf(f0.x); a[1] = f2bf(f0.y);                               \
            a[2] = f2bf(f0.z); a[3] = f2bf(f0.w);                               \
            a[4] = f2bf(f1.x); a[5] = f2bf(f1.y);                               \
            a[6] = f2bf(f1.z); a[7] = f2bf(f1.w);                               \
            if (mt == 0) afr0 = a; else afr1 = a;                               \
        }                                                                       \
        _Pragma("unroll")                                                       \
        for (int g = 0; g < 4; ++g) {                                           \
            acc[0][g] = __builtin_amdgcn_mfma_f32_16x16x32_bf16(                \
                afr0, (BARR)[g], acc[0][g], 0, 0, 0);                           \
            acc[1][g] = __builtin_amdgcn_mfma_f32_16x16x32_bf16(                \
                afr1, (BARR)[g], acc[1][g], 0, 0, 0);                           \
        }                                                                       \
    }

#define LOADB(DST, KT)                                                          \
    _Pragma("unroll")                                                           \
    for (int g = 0; g < 4; ++g) (DST)[g] = upw[((KT) * 4 + g) * 64 + lane];

__global__ __launch_bounds__(NTHREADS, 1)
void lstm_mfma(const int* __restrict__ x, const float* __restrict__ embWp,
               const bf16x8* __restrict__ up, float* __restrict__ out) {
    // h f32, double-buffered, f32-index XOR swizzle ^((row&15)<<2):
    // A-path ds_read_b128 at worst 2-way (free).
    __shared__ float hb[2][RTILE * DD];   // 2 x 32KB
    __shared__ int   xs[RTILE * TSTEPS];  // 2KB

    const int tid  = threadIdx.x;
    const int w    = tid >> 6;            // wave 0..15, d-slice [w*16, w*16+16)
    const int lane = tid & 63;
    const int l15  = lane & 15, lg = lane >> 4;
    const int base = blockIdx.x * RTILE;

    if (tid < RTILE * TSTEPS) xs[tid] = x[base * TSTEPS + tid];

    f32x4 acc[2][4];          // [mt][gate] = 32 regs
    float c[8];               // [mt*4 + j]
#pragma unroll
    for (int i = 0; i < 8; ++i) c[i] = 0.f;

    const bf16x8* upw = up + w * 2048;    // this wave's 32KB packed U slice

    // kt=0 B-fragments: permanently register-resident (U is step-invariant)
    bf16x8 bres[4];
    LOADB(bres, 0);

    __syncthreads();

#pragma unroll 1
    for (int t = 0; t < TSTEPS; ++t) {
        bf16x8 bA[4], bB[4];
        if (t > 0) { LOADB(bA, 1); }      // flies under the gather

        // ---- acc init: z = embW[x_t] gather (+b folded), 1 float4/(mt,j) ----
#pragma unroll
        for (int mt = 0; mt < 2; ++mt) {
#pragma unroll
            for (int j = 0; j < 4; ++j) {
                const int r    = mt * 16 + lg * 4 + j;        // C/D row
                const int xrow = xs[r * TSTEPS + t];
                const float4 g4 =
                    *(const float4*)(embWp + ((xrow * 16 + w) * 16 + l15) * 4);
                acc[mt][0][j] = g4.x; acc[mt][1][j] = g4.y;
                acc[mt][2][j] = g4.z; acc[mt][3][j] = g4.w;
            }
        }

        // ---- z += h @ U via MFMA, 2-deep software pipeline over kt ----
        if (t > 0) {
            const float* rb = hb[(t - 1) & 1];
            AFR_MFMA(0, bres)                 // resident, starts immediately
            LOADB(bB, 2) AFR_MFMA(1, bA)
            LOADB(bA, 3) AFR_MFMA(2, bB)
            LOADB(bB, 4) AFR_MFMA(3, bA)
            LOADB(bA, 5) AFR_MFMA(4, bB)
            LOADB(bB, 6) AFR_MFMA(5, bA)
            LOADB(bA, 7) AFR_MFMA(6, bB)
            AFR_MFMA(7, bA)
        }

        // ---- gate update (Keras i,f,g,o; identity candidate/output) ----
        float* wb = hb[t & 1];
#pragma unroll
        for (int mt = 0; mt < 2; ++mt) {
#pragma unroll
            for (int j = 0; j < 4; ++j) {
                const float zi = acc[mt][0][j];
                const float zf = acc[mt][1][j];
                const float zg = acc[mt][2][j];
                const float zo = acc[mt][3][j];
                const float ig = 1.f / (1.f + __expf(-zi));
                const float fg = 1.f / (1.f + __expf(-zf));
                const float og = 1.f / (1.f + __expf(-zo));
                const int   ci = mt * 4 + j;
                const float cn = fg * c[ci] + ig * zg;
                c[ci] = cn;
                const float h = og * cn;
                const int row = mt * 16 + lg * 4 + j;
                const int d   = w * 16 + l15;
                wb[(row * DD + d) ^ ((row & 15) << 2)] = h;
                if (t == TSTEPS - 1) out[(base + row) * DD + d] = h;
            }
        }
        __syncthreads();   // h(t) visible; prev-buffer reads done
    }
}

extern "C" void kernel_launch(void* const* d_in, const int* in_sizes, int n_in,
                              void* d_out, int out_size, void* d_ws, size_t ws_size,
                              hipStream_t stream) {
    const int*   x   = (const int*)d_in[0];
    const float* emb = (const float*)d_in[1];
    const float* W   = (const float*)d_in[2];
    const float* U   = (const float*)d_in[3];
    const float* b   = (const float*)d_in[4];
    float* out = (float*)d_out;

    float*  embWp = (float*)d_ws;                          // 620KB
    bf16x8* up    = (bf16x8*)((char*)d_ws + (1 << 20));    // 512KB at +1MB

    embw_kernel<<<NCHAR, 256, 0, stream>>>(emb, W, b, embWp);
    upack_kernel<<<128, 256, 0, stream>>>(U, up);
    lstm_mfma<<<NBLOCKS, NTHREADS, 0, stream>>>(x, embWp, up, out);
}

// Round 8
// 174.452 us; speedup vs baseline: 2.3339x; 2.3339x over previous
//
#include <hip/hip_runtime.h>
#include <hip/hip_bf16.h>

// EmbeddingRNN via MFMA, round 8: ZERO-SPILL design for the 128-VGPR budget
// that 512-thread blocks empirically always receive (law: VGPR cap =
// 65536/blockDim; launch_bounds 2nd arg / waves_per_eu do NOT raise it).
// Spill signature from R2-R7: WRITE_SIZE > 8.2MB(=out) == scratch writes;
// FETCH tracks spill re-fills thrashing L2 -> HBM latency on critical path.
// Cuts vs R2: c[] -> LDS; h bf16 single-buffer (A-frag = 1 ds_read_b128, no
// cvt chain); kt loop FORCED ROLLED so the scheduler can't hoist 64 B-loads.
// Static live ~116 <= 128.
//   phase 0a: embWp = pack(emb @ W + b)  (155 x 1024 f32, float4-gatherable)
//   phase 0b: Upack = U as bf16 MFMA B-fragments, 8-wave-slice-major
//   phase 1:  256 blocks x 8 waves x 32 rows, 16 steps fused; 2 barriers/step.

#define DD      256
#define G4      1024
#define NCHAR   155
#define TSTEPS  16
#define RTILE   32
#define NROWS   8192
#define NBLOCKS (NROWS / RTILE)   // 256
#define NTHREADS 512              // 8 waves; wave w owns d-slice [w*32, w*32+32)

typedef __attribute__((ext_vector_type(8))) short bf16x8;
typedef __attribute__((ext_vector_type(4))) float f32x4;

__device__ inline unsigned short f2bf_bits(float f) {
    __hip_bfloat16 h = __float2bfloat16(f);   // RTNE
    return *reinterpret_cast<unsigned short*>(&h);
}

// ---------------- phase 0a: embWp = pack(emb @ W + b) ----------------
// value (char i, gate g, col d): w=d>>5, l15=d&15, nn=(d>>4)&1, nt=g*2+nn
// embWp[ ((i*8 + w)*16 + l15)*8 + nt ]
__global__ __launch_bounds__(256)
void embw_kernel(const float* __restrict__ emb, const float* __restrict__ W,
                 const float* __restrict__ b, float* __restrict__ embWp) {
    const int i   = blockIdx.x;
    const int tid = threadIdx.x;
    float a0 = b[tid], a1 = b[256 + tid], a2 = b[512 + tid], a3 = b[768 + tid];
    const float* er = emb + i * DD;
    for (int k = 0; k < DD; ++k) {
        const float e = er[k];
        const float* wr = W + k * G4 + tid;
        a0 += e * wr[0];
        a1 += e * wr[256];
        a2 += e * wr[512];
        a3 += e * wr[768];
    }
    const int w = tid >> 5, l15 = tid & 15, nn = (tid >> 4) & 1;
    float* o = embWp + ((i * 8 + w) * 16 + l15) * 8 + nn;
    o[0] = a0; o[2] = a1; o[4] = a2; o[6] = a3;   // nt = g*2+nn
}

// ---------------- phase 0b: pack U into bf16 MFMA B-fragments ----------------
// up[((w*8 + kt)*8 + nt)*64 + lane]: lane l holds
//   U[kt*32+(l>>4)*8+j][g*256 + w*32 + nn*16 + (l&15)], nt=g*2+nn
__global__ __launch_bounds__(256)
void upack_kernel(const float* __restrict__ U, bf16x8* __restrict__ up) {
    const int gid  = blockIdx.x * 256 + threadIdx.x;   // 32768 total
    const int lane = gid & 63;
    const int nt   = (gid >> 6) & 7;
    const int kt   = (gid >> 9) & 7;
    const int w    = gid >> 12;
    const int g = nt >> 1, nn = nt & 1;
    const int col = g * 256 + w * 32 + nn * 16 + (lane & 15);
    const int k0  = kt * 32 + (lane >> 4) * 8;
    bf16x8 v;
#pragma unroll
    for (int j = 0; j < 8; ++j) v[j] = (short)f2bf_bits(U[(k0 + j) * G4 + col]);
    up[gid] = v;
}

// ---------------- phase 1: fused recurrence ----------------
__global__ __launch_bounds__(NTHREADS)
void lstm_mfma(const int* __restrict__ x, const float* __restrict__ embWp,
               const bf16x8* __restrict__ up, float* __restrict__ out) {
    // h: bf16, single buffer, byte-swizzle ^((row&7)<<4) (R3-proven pattern).
    // c: f32 in LDS, padded stride 257 (each thread RMWs only its own slots).
    __shared__ __align__(16) unsigned short hb[RTILE * DD];  // 16KB
    __shared__ float cb[RTILE * 257];                        // ~32KB
    __shared__ int   xs[RTILE * TSTEPS];                     // 2KB

    const int tid  = threadIdx.x;
    const int w    = tid >> 6;
    const int lane = tid & 63;
    const int l15  = lane & 15, lg = lane >> 4;
    const int base = blockIdx.x * RTILE;

    xs[tid] = x[base * TSTEPS + tid];

    f32x4 acc[2][8];   // 64 VGPRs — the dominant live block

    // zero this thread's 16 c-slots (covers all 32x256 across 512 threads)
#pragma unroll
    for (int mt = 0; mt < 2; ++mt)
#pragma unroll
        for (int nn = 0; nn < 2; ++nn)
#pragma unroll
            for (int j = 0; j < 4; ++j)
                cb[(mt * 16 + lg * 4 + j) * 257 + w * 32 + nn * 16 + l15] = 0.f;

    const bf16x8* upw = up + w * 4096;    // this wave's 64KB packed U slice

    __syncthreads();

#pragma unroll 1
    for (int t = 0; t < TSTEPS; ++t) {
        // ---- acc init: z = embW[x_t] gather (+b folded), 2 float4/(mt,j) ----
#pragma unroll
        for (int mt = 0; mt < 2; ++mt) {
#pragma unroll
            for (int j = 0; j < 4; ++j) {
                const int r    = mt * 16 + lg * 4 + j;        // C/D row
                const int xrow = xs[r * TSTEPS + t];
                const float4* ew =
                    (const float4*)(embWp + ((xrow * 8 + w) * 16 + l15) * 8);
                const float4 g0 = ew[0];
                const float4 g1 = ew[1];
                acc[mt][0][j] = g0.x; acc[mt][1][j] = g0.y;
                acc[mt][2][j] = g0.z; acc[mt][3][j] = g0.w;
                acc[mt][4][j] = g1.x; acc[mt][5][j] = g1.y;
                acc[mt][6][j] = g1.z; acc[mt][7][j] = g1.w;
            }
        }

        // ---- z += h @ U via MFMA; kt loop ROLLED to pin register pressure ----
        if (t > 0) {
            const char* rbb = (const char*)hb;
            const bf16x8* upk = upw;
#pragma unroll 1
            for (int kt = 0; kt < 8; ++kt) {
                bf16x8 bfr[8];
#pragma unroll
                for (int nt = 0; nt < 8; ++nt)
                    bfr[nt] = upk[nt * 64 + lane];   // 1KB coalesced, L2

                bf16x8 afr0, afr1;
                {
                    const int row0 = l15;
                    const int row1 = 16 + l15;
                    const int kb   = (kt * 32 + lg * 8) * 2;   // byte offset in row
                    afr0 = *(const bf16x8*)(rbb + ((row0 * 512 + kb) ^ ((row0 & 7) << 4)));
                    afr1 = *(const bf16x8*)(rbb + ((row1 * 512 + kb) ^ ((row1 & 7) << 4)));
                }
#pragma unroll
                for (int nt = 0; nt < 8; ++nt) {
                    acc[0][nt] = __builtin_amdgcn_mfma_f32_16x16x32_bf16(
                        afr0, bfr[nt], acc[0][nt], 0, 0, 0);
                    acc[1][nt] = __builtin_amdgcn_mfma_f32_16x16x32_bf16(
                        afr1, bfr[nt], acc[1][nt], 0, 0, 0);
                }
                upk += 512;
            }
        }

        __syncthreads();   // all A-reads of h(t-1) done before overwrite

        // ---- gate update (Keras i,f,g,o; identity candidate/output) ----
#pragma unroll
        for (int mt = 0; mt < 2; ++mt) {
#pragma unroll
            for (int nn = 0; nn < 2; ++nn) {
#pragma unroll
                for (int j = 0; j < 4; ++j) {
                    const float zi = acc[mt][0 + nn][j];
                    const float zf = acc[mt][2 + nn][j];
                    const float zg = acc[mt][4 + nn][j];
                    const float zo = acc[mt][6 + nn][j];
                    const float ig = 1.f / (1.f + __expf(-zi));
                    const float fg = 1.f / (1.f + __expf(-zf));
                    const float og = 1.f / (1.f + __expf(-zo));
                    const int row = mt * 16 + lg * 4 + j;
                    const int d   = w * 32 + nn * 16 + l15;
                    float* cp = &cb[row * 257 + d];
                    const float cn = fg * (*cp) + ig * zg;
                    *cp = cn;
                    const float h = og * cn;
                    *(unsigned short*)((char*)hb +
                        ((row * 512 + d * 2) ^ ((row & 7) << 4))) = f2bf_bits(h);
                    if (t == TSTEPS - 1) out[(base + row) * DD + d] = h;
                }
            }
        }
        __syncthreads();   // h(t) visible for next step's A-reads
    }
}

extern "C" void kernel_launch(void* const* d_in, const int* in_sizes, int n_in,
                              void* d_out, int out_size, void* d_ws, size_t ws_size,
                              hipStream_t stream) {
    const int*   x   = (const int*)d_in[0];
    const float* emb = (const float*)d_in[1];
    const float* W   = (const float*)d_in[2];
    const float* U   = (const float*)d_in[3];
    const float* b   = (const float*)d_in[4];
    float* out = (float*)d_out;

    float*  embWp = (float*)d_ws;                          // 620KB
    bf16x8* up    = (bf16x8*)((char*)d_ws + (1 << 20));    // 512KB at +1MB

    embw_kernel<<<NCHAR, 256, 0, stream>>>(emb, W, b, embWp);
    upack_kernel<<<128, 256, 0, stream>>>(U, up);
    lstm_mfma<<<NBLOCKS, NTHREADS, 0, stream>>>(x, embWp, up, out);
}

// Round 9
// 144.629 us; speedup vs baseline: 2.8151x; 1.2062x over previous
//
#include <hip/hip_runtime.h>
#include <hip/hip_bf16.h>

// EmbeddingRNN via MFMA, round 9 = R8 (zero-spill, 174us) + latency fixes:
//  (1) 2-deep software pipeline over kt (static bA/bB, ktp loop rolled,
//      body 2x-unrolled): next kt's 8 B-loads are in the L2 queue before the
//      current kt's MFMAs execute -> stream at L2 BW instead of paying the
//      loaded round-trip latency per kt. (R8 gap analysis: rolled loop with
//      zero load-ahead + barrier-aligned waves = queue empties every kt.)
//  (2) h double-buffered bf16 -> ONE barrier/step (reads prev buf, writes cur).
//  (3) sigmoid via v_rcp_f32 (no fast-math full divides: 48/step/wave @ ~10
//      inst each). rcp rel err ~1e-7, negligible vs 2.4e-4 margin.
// Register budget law (R2-R8): 512-thr blocks get a 128-VGPR cap; R8 used 76;
// +32 for the second B buffer => ~110. WRITE_SIZE==8.2MB is the spill-meter.

#define DD      256
#define G4      1024
#define NCHAR   155
#define TSTEPS  16
#define RTILE   32
#define NROWS   8192
#define NBLOCKS (NROWS / RTILE)   // 256
#define NTHREADS 512              // 8 waves; wave w owns d-slice [w*32, w*32+32)

typedef __attribute__((ext_vector_type(8))) short bf16x8;
typedef __attribute__((ext_vector_type(4))) float f32x4;

__device__ inline unsigned short f2bf_bits(float f) {
    __hip_bfloat16 h = __float2bfloat16(f);   // RTNE
    return *reinterpret_cast<unsigned short*>(&h);
}

__device__ inline float sigmoid_fast(float x) {
    return __builtin_amdgcn_rcpf(1.f + __expf(-x));
}

// ---------------- phase 0a: embWp = pack(emb @ W + b) ----------------
// value (char i, gate g, col d): w=d>>5, l15=d&15, nn=(d>>4)&1, nt=g*2+nn
// embWp[ ((i*8 + w)*16 + l15)*8 + nt ]
__global__ __launch_bounds__(256)
void embw_kernel(const float* __restrict__ emb, const float* __restrict__ W,
                 const float* __restrict__ b, float* __restrict__ embWp) {
    const int i   = blockIdx.x;
    const int tid = threadIdx.x;
    float a0 = b[tid], a1 = b[256 + tid], a2 = b[512 + tid], a3 = b[768 + tid];
    const float* er = emb + i * DD;
    for (int k = 0; k < DD; ++k) {
        const float e = er[k];
        const float* wr = W + k * G4 + tid;
        a0 += e * wr[0];
        a1 += e * wr[256];
        a2 += e * wr[512];
        a3 += e * wr[768];
    }
    const int w = tid >> 5, l15 = tid & 15, nn = (tid >> 4) & 1;
    float* o = embWp + ((i * 8 + w) * 16 + l15) * 8 + nn;
    o[0] = a0; o[2] = a1; o[4] = a2; o[6] = a3;   // nt = g*2+nn
}

// ---------------- phase 0b: pack U into bf16 MFMA B-fragments ----------------
// up[((w*8 + kt)*8 + nt)*64 + lane]: lane l holds
//   U[kt*32+(l>>4)*8+j][g*256 + w*32 + nn*16 + (l&15)], nt=g*2+nn
__global__ __launch_bounds__(256)
void upack_kernel(const float* __restrict__ U, bf16x8* __restrict__ up) {
    const int gid  = blockIdx.x * 256 + threadIdx.x;   // 32768 total
    const int lane = gid & 63;
    const int nt   = (gid >> 6) & 7;
    const int kt   = (gid >> 9) & 7;
    const int w    = gid >> 12;
    const int g = nt >> 1, nn = nt & 1;
    const int col = g * 256 + w * 32 + nn * 16 + (lane & 15);
    const int k0  = kt * 32 + (lane >> 4) * 8;
    bf16x8 v;
#pragma unroll
    for (int j = 0; j < 8; ++j) v[j] = (short)f2bf_bits(U[(k0 + j) * G4 + col]);
    up[gid] = v;
}

// ---------------- phase 1: fused recurrence ----------------

#define LOADB(DST, KT)                                                          \
    _Pragma("unroll")                                                           \
    for (int nt = 0; nt < 8; ++nt) (DST)[nt] = upw[((KT) * 8 + nt) * 64 + lane];

// A-frags for (runtime) K-tile KT from swizzled bf16 LDS, then 16 MFMAs
#define AFR_MFMA(KT, BARR)                                                      \
    {                                                                           \
        const int kb = ((KT) * 32 + lg * 8) * 2;                                \
        const int r0 = l15, r1 = 16 + l15;                                      \
        bf16x8 afr0 = *(const bf16x8*)(rbb + ((r0 * 512 + kb) ^ ((r0 & 7) << 4))); \
        bf16x8 afr1 = *(const bf16x8*)(rbb + ((r1 * 512 + kb) ^ ((r1 & 7) << 4))); \
        _Pragma("unroll")                                                       \
        for (int nt = 0; nt < 8; ++nt) {                                        \
            acc[0][nt] = __builtin_amdgcn_mfma_f32_16x16x32_bf16(               \
                afr0, (BARR)[nt], acc[0][nt], 0, 0, 0);                         \
            acc[1][nt] = __builtin_amdgcn_mfma_f32_16x16x32_bf16(               \
                afr1, (BARR)[nt], acc[1][nt], 0, 0, 0);                         \
        }                                                                       \
    }

__global__ __launch_bounds__(NTHREADS)
void lstm_mfma(const int* __restrict__ x, const float* __restrict__ embWp,
               const bf16x8* __restrict__ up, float* __restrict__ out) {
    // h: bf16, DOUBLE buffer, byte-swizzle ^((row&7)<<4) -> 1 barrier/step.
    // c: f32 in LDS, stride 257 (thread-private slots, no sync needed).
    __shared__ __align__(16) unsigned short hb[2][RTILE * DD];  // 32KB
    __shared__ float cb[RTILE * 257];                           // ~33KB
    __shared__ int   xs[RTILE * TSTEPS];                        // 2KB

    const int tid  = threadIdx.x;
    const int w    = tid >> 6;
    const int lane = tid & 63;
    const int l15  = lane & 15, lg = lane >> 4;
    const int base = blockIdx.x * RTILE;

    xs[tid] = x[base * TSTEPS + tid];

    f32x4 acc[2][8];   // 64 accumulator regs (AGPR-eligible)

    // zero this thread's 16 c-slots
#pragma unroll
    for (int mt = 0; mt < 2; ++mt)
#pragma unroll
        for (int nn = 0; nn < 2; ++nn)
#pragma unroll
            for (int j = 0; j < 4; ++j)
                cb[(mt * 16 + lg * 4 + j) * 257 + w * 32 + nn * 16 + l15] = 0.f;

    const bf16x8* upw = up + w * 4096;    // this wave's 64KB packed U slice

    __syncthreads();

#pragma unroll 1
    for (int t = 0; t < TSTEPS; ++t) {
        // ---- acc init: z = embW[x_t] gather (+b folded), 2 float4/(mt,j) ----
        // (issued first; B-prologue loads below fly concurrently)
#pragma unroll
        for (int mt = 0; mt < 2; ++mt) {
#pragma unroll
            for (int j = 0; j < 4; ++j) {
                const int r    = mt * 16 + lg * 4 + j;        // C/D row
                const int xrow = xs[r * TSTEPS + t];
                const float4* ew =
                    (const float4*)(embWp + ((xrow * 8 + w) * 16 + l15) * 8);
                const float4 g0 = ew[0];
                const float4 g1 = ew[1];
                acc[mt][0][j] = g0.x; acc[mt][1][j] = g0.y;
                acc[mt][2][j] = g0.z; acc[mt][3][j] = g0.w;
                acc[mt][4][j] = g1.x; acc[mt][5][j] = g1.y;
                acc[mt][6][j] = g1.z; acc[mt][7][j] = g1.w;
            }
        }

        // ---- z += h @ U via MFMA; 2-deep kt pipeline (queue never empties) ----
        if (t > 0) {
            const char* rbb = (const char*)hb[(t - 1) & 1];
            bf16x8 bA[8], bB[8];
            LOADB(bA, 0)                      // prologue; overlaps gather
#pragma unroll 1
            for (int ktp = 0; ktp < 4; ++ktp) {
                const int kt0 = ktp * 2, kt1 = kt0 + 1;
                LOADB(bB, kt1)                // in queue before bA's MFMAs
                AFR_MFMA(kt0, bA)
                if (ktp < 3) { LOADB(bA, kt0 + 2) }
                AFR_MFMA(kt1, bB)
            }
        }

        // ---- gate update (Keras i,f,g,o; identity candidate/output) ----
        {
            char* wbb = (char*)hb[t & 1];
#pragma unroll
            for (int mt = 0; mt < 2; ++mt) {
#pragma unroll
                for (int nn = 0; nn < 2; ++nn) {
#pragma unroll
                    for (int j = 0; j < 4; ++j) {
                        const float zi = acc[mt][0 + nn][j];
                        const float zf = acc[mt][2 + nn][j];
                        const float zg = acc[mt][4 + nn][j];
                        const float zo = acc[mt][6 + nn][j];
                        const float ig = sigmoid_fast(zi);
                        const float fg = sigmoid_fast(zf);
                        const float og = sigmoid_fast(zo);
                        const int row = mt * 16 + lg * 4 + j;
                        const int d   = w * 32 + nn * 16 + l15;
                        float* cp = &cb[row * 257 + d];
                        const float cn = fg * (*cp) + ig * zg;
                        *cp = cn;
                        const float h = og * cn;
                        *(unsigned short*)(wbb +
                            ((row * 512 + d * 2) ^ ((row & 7) << 4))) = f2bf_bits(h);
                        if (t == TSTEPS - 1) out[(base + row) * DD + d] = h;
                    }
                }
            }
        }
        __syncthreads();   // publish h(t); prev-buffer reads already done
    }
}

extern "C" void kernel_launch(void* const* d_in, const int* in_sizes, int n_in,
                              void* d_out, int out_size, void* d_ws, size_t ws_size,
                              hipStream_t stream) {
    const int*   x   = (const int*)d_in[0];
    const float* emb = (const float*)d_in[1];
    const float* W   = (const float*)d_in[2];
    const float* U   = (const float*)d_in[3];
    const float* b   = (const float*)d_in[4];
    float* out = (float*)d_out;

    float*  embWp = (float*)d_ws;                          // 620KB
    bf16x8* up    = (bf16x8*)((char*)d_ws + (1 << 20));    // 512KB at +1MB

    embw_kernel<<<NCHAR, 256, 0, stream>>>(emb, W, b, embWp);
    upack_kernel<<<128, 256, 0, stream>>>(U, up);
    lstm_mfma<<<NBLOCKS, NTHREADS, 0, stream>>>(x, embWp, up, out);
}